// Round 17
// baseline (389.816 us; speedup 1.0000x reference)
//
#include <hip/hip_runtime.h>
#include <hip/hip_bf16.h>
#include <math.h>

#define BB 4
#define LL 2048
#define DM 512
#define NH 8
#define DK 64
#define RANK 20

typedef __attribute__((ext_vector_type(8))) short short8;
typedef __attribute__((ext_vector_type(4))) short short4b;
typedef __attribute__((ext_vector_type(4))) float f32x4;
typedef __hip_bfloat16 bf16;

__device__ inline short to_bf(float x) {
    bf16 h = __float2bfloat16(x);
    return *reinterpret_cast<short*>(&h);
}
__device__ inline unsigned pk2(float lo, float hi) {
    return ((unsigned)(unsigned short)to_bf(hi) << 16) |
           (unsigned)(unsigned short)to_bf(lo);
}

// ---------------- build W^T (bf16) from TT cores, all 4 sets ----------------
struct BwArgs {
    const float* g1[4]; const float* g2[4]; const float* g3[4]; const float* g4[4];
    bf16* wt[4];
};
__global__ __launch_bounds__(256) void build_w_kernel(BwArgs args)
{
    int s4 = blockIdx.y;
    const float* __restrict__ g1 = args.g1[s4];
    const float* __restrict__ g2 = args.g2[s4];
    const float* __restrict__ g3 = args.g3[s4];
    const float* __restrict__ g4 = args.g4[s4];
    bf16* __restrict__ Wt = args.wt[s4];

    int idx = blockIdx.x * 256 + threadIdx.x;
    if (idx >= 4*4*8*4*4*8) return;
    int q = idx & 7; int t = idx >> 3;
    int p = t & 3;  t >>= 2;
    int o = t & 3;  t >>= 2;
    int y = t & 7;  t >>= 3;
    int x = t & 3;  t >>= 2;
    int w = t & 3;

    float c[RANK];
    for (int v = 0; v < RANK; ++v) c[v] = 0.f;
    for (int u = 0; u < RANK; ++u) {
        float a = g1[(w*4 + o)*RANK + u];
        const float* g2p = g2 + ((u*4 + x)*4 + p)*RANK;
        for (int v = 0; v < RANK; ++v) c[v] += a * g2p[v];
    }
    float d[RANK];
    for (int r = 0; r < RANK; ++r) d[r] = 0.f;
    for (int v = 0; v < RANK; ++v) {
        float cv = c[v];
        const float* g3p = g3 + ((v*8 + y)*8 + q)*RANK;
        for (int r = 0; r < RANK; ++r) d[r] += cv * g3p[r];
    }
    for (int z = 0; z < 4; ++z) {
        for (int s = 0; s < 4; ++s) {
            float acc = 0.f;
            for (int r = 0; r < RANK; ++r) acc += d[r] * g4[(r*4 + z)*4 + s];
            int i = ((w*4 + x)*8 + y)*4 + z;
            int j = ((o*4 + p)*8 + q)*4 + s;
            Wt[(size_t)j*DM + i] = __float2bfloat16(acc);
        }
    }
}

// ---------------- fp32 -> bf16 convert (q,k,v), 16 elems/thread ----------------
struct CvtArgs { const float* src[3]; bf16* dst[3]; };
__global__ __launch_bounds__(256) void cvt_kernel(CvtArgs args)
{
    int a = blockIdx.y;
    const float* __restrict__ s = args.src[a];
    bf16* __restrict__ d = args.dst[a];
    size_t i = ((size_t)blockIdx.x * 256 + threadIdx.x) * 16;
    #pragma unroll
    for (int half = 0; half < 2; ++half) {
        float4 v0 = *(const float4*)&s[i + half*8];
        float4 v1 = *(const float4*)&s[i + half*8 + 4];
        short8 h;
        h[0] = to_bf(v0.x); h[1] = to_bf(v0.y); h[2] = to_bf(v0.z); h[3] = to_bf(v0.w);
        h[4] = to_bf(v1.x); h[5] = to_bf(v1.y); h[6] = to_bf(v1.z); h[7] = to_bf(v1.w);
        *(short8*)&d[i + half*8] = h;
    }
}

// ---------------- LDS-free MFMA GEMM core: block 128x64, wave 64x32 ----------
#define GEMM_CORE128x64(Ap, Bp)                                                    \
    f32x4 acc[4][2] = {};                                                          \
    for (int k0 = 0; k0 < DM; k0 += 32) {                                          \
        short8 a[4], b[2];                                                         \
        _Pragma("unroll")                                                          \
        for (int mt = 0; mt < 4; ++mt)                                             \
            a[mt] = *(const short8*)&Ap[(size_t)(mt*16 + l15)*DM + k0 + l4*8];     \
        _Pragma("unroll")                                                          \
        for (int nt = 0; nt < 2; ++nt)                                             \
            b[nt] = *(const short8*)&Bp[(size_t)(nt*16 + l15)*DM + k0 + l4*8];     \
        _Pragma("unroll")                                                          \
        for (int mt = 0; mt < 4; ++mt)                                             \
            _Pragma("unroll")                                                      \
            for (int nt = 0; nt < 2; ++nt)                                         \
                acc[mt][nt] = __builtin_amdgcn_mfma_f32_16x16x32_bf16(             \
                    a[mt], b[nt], acc[mt][nt], 0, 0, 0);                           \
    }

// q/k/v projections fused: z=0 q (scaled by log2e/8, head layout), z=1 k,
// z=2 v (transposed [bh][d][l])
struct QkvArgs {
    const bf16* A[3]; const bf16* W[3]; const float* bias[3];
    bf16* outQ; bf16* outK; bf16* outV;
};
__global__ __launch_bounds__(256) void gemm_qkv_kernel(QkvArgs args)
{
    int z = blockIdx.z;
    const bf16* __restrict__ A  = args.A[z];
    const bf16* __restrict__ Wt = args.W[z];
    const float* __restrict__ bias = args.bias[z];

    int m0 = blockIdx.x * 128, n0 = blockIdx.y * 64;
    int t = threadIdx.x, lane = t & 63, wave = t >> 6;
    int l15 = lane & 15, l4 = lane >> 4;
    int wm = wave >> 1, wn = wave & 1;
    const bf16* Ap = A  + (size_t)(m0 + wm*64)*DM;
    const bf16* Bp = Wt + (size_t)(n0 + wn*32)*DM;

    GEMM_CORE128x64(Ap, Bp)

    if (z < 2) {
        bf16* __restrict__ out = (z == 0) ? args.outQ : args.outK;
        // 0.125 * log2(e): fold softmax scale + exp2 conversion into Q
        float oscale = (z == 0) ? 0.18033688f : 1.0f;
        #pragma unroll
        for (int mt = 0; mt < 4; ++mt) {
            #pragma unroll
            for (int r = 0; r < 4; ++r) {
                int m = m0 + wm*64 + mt*16 + l4*4 + r;
                int l = m & (LL-1), bb = m >> 11;
                #pragma unroll
                for (int nt = 0; nt < 2; ++nt) {
                    int n = n0 + wn*32 + nt*16 + l15;
                    int h = n >> 6, d = n & 63;
                    float val = (acc[mt][nt][r] + bias[n]) * oscale;
                    out[(((size_t)(bb*NH + h))*LL + l)*DK + d] = __float2bfloat16(val);
                }
            }
        }
    } else {
        // transposed store: vt[(bh*DK + d)*LL + l]
        #pragma unroll
        for (int mt = 0; mt < 4; ++mt) {
            int mbase = m0 + wm*64 + mt*16 + l4*4;
            int l = mbase & (LL-1), bb = mbase >> 11;
            #pragma unroll
            for (int nt = 0; nt < 2; ++nt) {
                int n = n0 + wn*32 + nt*16 + l15;
                int h = n >> 6, d = n & 63;
                float bv = bias[n];
                short4b h4;
                #pragma unroll
                for (int r = 0; r < 4; ++r) h4[r] = to_bf(acc[mt][nt][r] + bv);
                *(short4b*)&args.outV[((size_t)(bb*NH + h)*DK + d)*LL + l] = h4;
            }
        }
    }
}

// fc GEMM: A = o (bf16 row-major), out fp32 row-major + bias
__global__ __launch_bounds__(256) void gemm_fc_kernel(
    const bf16* __restrict__ A, const bf16* __restrict__ Wt,
    const float* __restrict__ bias, float* __restrict__ out)
{
    int m0 = blockIdx.x * 128, n0 = blockIdx.y * 64;
    int t = threadIdx.x, lane = t & 63, wave = t >> 6;
    int l15 = lane & 15, l4 = lane >> 4;
    int wm = wave >> 1, wn = wave & 1;
    const bf16* Ap = A  + (size_t)(m0 + wm*64)*DM;
    const bf16* Bp = Wt + (size_t)(n0 + wn*32)*DM;

    GEMM_CORE128x64(Ap, Bp)

    #pragma unroll
    for (int mt = 0; mt < 4; ++mt) {
        #pragma unroll
        for (int r = 0; r < 4; ++r) {
            int m = m0 + wm*64 + mt*16 + l4*4 + r;
            #pragma unroll
            for (int nt = 0; nt < 2; ++nt) {
                int n = n0 + wn*32 + nt*16 + l15;
                out[(size_t)m*DM + n] = acc[mt][nt][r] + bias[n];
            }
        }
    }
}

// ---------------- attention pass A: 32 q-rows/wave, lsum + PV + O + invl ------
// XCD-swizzled 1D grid: all 16 q-tiles of one bh land on one XCD so its
// K+V (512 KB) stay L2-resident (4 bh x 512 KB = 2 MB per 4 MB L2).
__global__ __launch_bounds__(256, 2) void attn_a_kernel(
    const bf16* __restrict__ Qh, const bf16* __restrict__ Kh,
    const bf16* __restrict__ Vt, float* __restrict__ invl_g,
    bf16* __restrict__ O)
{
    __shared__ __align__(16) bf16 Ks[128*64];       // 16 KB
    __shared__ __align__(16) bf16 Ps[4][32*128];    // 32 KB  (row q: 256B)
    __shared__ float invlS[4][32];

    int bid = blockIdx.x;                  // 512 blocks, XCD = bid & 7
    int xcd = bid & 7, j = bid >> 3;
    int bh = xcd + 8 * (j & 3);
    int qt = j >> 2;
    int q0 = qt * 128;
    int t = threadIdx.x, lane = t & 63, wave = t >> 6;
    int l15 = lane & 15, l4 = lane >> 4;
    int qr0 = wave * 32;

    const bf16* Qp = Qh + ((size_t)bh * LL + q0 + qr0) * DK;
    const bf16* Kp = Kh + (size_t)bh * LL * DK;
    const bf16* Vp = Vt + (size_t)bh * DK * LL;

    short8 aq0[2], aq1[2];
    #pragma unroll
    for (int f = 0; f < 2; ++f) {
        aq0[f] = *(const short8*)&Qp[(size_t)(f*16 + l15)*DK + l4*8];
        aq1[f] = *(const short8*)&Qp[(size_t)(f*16 + l15)*DK + 32 + l4*8];
    }

    int srow = t >> 3, sseg = t & 7;       // staging: 32 rows x 8 16B-segs x4
    int swr = (l15 & 7) << 4;              // swizzle key (q&7 == l15&7 for both frags)

    float lsum[2] = {0.f, 0.f};
    f32x4 o_acc[2][4] = {};

    for (int kc = 0; kc < LL; kc += 128) {
        #pragma unroll
        for (int i = 0; i < 4; ++i) {
            int row = srow + i*32;
            int off = (sseg*16) ^ ((row & 7) << 4);
            *(short8*)&Ks[row*64 + (off >> 1)] =
                *(const short8*)&Kp[(size_t)(kc + row)*DK + sseg*8];
        }
        __syncthreads();

        // prefetch V fragments for this chunk (consumed after QK -> latency hidden)
        short8 vf[16];
        #pragma unroll
        for (int kt = 0; kt < 4; ++kt)
            #pragma unroll
            for (int dt = 0; dt < 4; ++dt)
                vf[kt*4 + dt] =
                    *(const short8*)&Vp[(size_t)(dt*16 + l15)*LL + kc + kt*32 + l4*8];

        #pragma unroll
        for (int ct = 0; ct < 8; ++ct) {
            int rb = (ct*16 + l15) * 64;
            short8 k0f = *(const short8*)&Ks[rb + (((l4*16) ^ swr) >> 1)];
            short8 k1f = *(const short8*)&Ks[rb + (((64 + l4*16) ^ swr) >> 1)];
            #pragma unroll
            for (int f = 0; f < 2; ++f) {
                f32x4 s = {0.f, 0.f, 0.f, 0.f};
                s = __builtin_amdgcn_mfma_f32_16x16x32_bf16(k0f, aq0[f], s, 0, 0, 0);
                s = __builtin_amdgcn_mfma_f32_16x16x32_bf16(k1f, aq1[f], s, 0, 0, 0);
                float p0 = exp2f(s[0]), p1 = exp2f(s[1]);
                float p2 = exp2f(s[2]), p3 = exp2f(s[3]);
                lsum[f] += (p0 + p1) + (p2 + p3);
                uint2 w2;
                w2.x = pk2(p0, p1);
                w2.y = pk2(p2, p3);
                int kb = (ct*32 + l4*8) ^ swr;
                *(uint2*)((char*)&Ps[wave][(f*16 + l15)*128] + kb) = w2;
            }
        }

        #pragma unroll
        for (int f = 0; f < 2; ++f)
            #pragma unroll
            for (int kt = 0; kt < 4; ++kt) {
                short8 a = *(const short8*)
                    &Ps[wave][(f*16 + l15)*128 + (((kt*64 + l4*16) ^ swr) >> 1)];
                #pragma unroll
                for (int dt = 0; dt < 4; ++dt)
                    o_acc[f][dt] = __builtin_amdgcn_mfma_f32_16x16x32_bf16(
                        a, vf[kt*4 + dt], o_acc[f][dt], 0, 0, 0);
            }
        __syncthreads();
    }

    // reduce lsum across the 4 l4-groups (lanes sharing q = l15 within a frag)
    #pragma unroll
    for (int f = 0; f < 2; ++f) {
        float ss = lsum[f];
        ss += __shfl_xor(ss, 16);
        ss += __shfl_xor(ss, 32);
        float inv = 1.0f / ss;
        if (l4 == 0) {
            invl_g[(size_t)bh * LL + q0 + qr0 + f*16 + l15] = inv;
            invlS[wave][f*16 + l15] = inv;
        }
    }

    // write O = o_acc * invl (bf16)
    int bb = bh >> 3, h = bh & 7;
    #pragma unroll
    for (int f = 0; f < 2; ++f) {
        f32x4 iv = *(f32x4*)&invlS[wave][f*16 + l4*4];
        #pragma unroll
        for (int dt = 0; dt < 4; ++dt)
            #pragma unroll
            for (int r = 0; r < 4; ++r) {
                int row = q0 + qr0 + f*16 + l4*4 + r;
                O[((size_t)bb * LL + row) * DM + h*DK + dt*16 + l15] =
                    __float2bfloat16(o_acc[f][dt][r] * iv[r]);
            }
    }
}

// ---------------- attention pass B: normalized-P streamer, 2 Q-frags/wave ----
// XCD-swizzled 1D grid: same bh pinned to same XCD for K L2 residence.
__global__ __launch_bounds__(256, 4) void attn_p_kernel(
    const bf16* __restrict__ Qh, const bf16* __restrict__ Kh,
    const float* __restrict__ invl_g, float* __restrict__ attn)
{
    __shared__ __align__(16) bf16 Ks[256*64];       // 32 KB, swizzled rows

    int bid = blockIdx.x;                  // 4096 blocks, XCD = bid & 7
    int xcd = bid & 7, j = bid >> 3;
    int bh = xcd + 8 * (j & 3);
    int rest = j >> 2;                     // [0,128)
    int qt = rest & 15;
    int ko = rest >> 4;                    // [0,8)
    int kc0 = ko * 256, q0 = qt * 128;
    int t = threadIdx.x, lane = t & 63, wave = t >> 6;
    int l15 = lane & 15, l4 = lane >> 4;
    int qr0 = wave * 32;

    const bf16* Qp = Qh + ((size_t)bh * LL + q0 + qr0) * DK;
    const bf16* Kp = Kh + ((size_t)bh * LL + kc0) * DK;

    // two Q fragments (B-operand) per wave
    short8 bq0[2], bq1[2];
    float inv[2];
    #pragma unroll
    for (int f = 0; f < 2; ++f) {
        bq0[f] = *(const short8*)&Qp[(size_t)(f*16 + l15)*DK + l4*8];
        bq1[f] = *(const short8*)&Qp[(size_t)(f*16 + l15)*DK + 32 + l4*8];
        inv[f] = invl_g[(size_t)bh * LL + q0 + qr0 + f*16 + l15];
    }

    // stage 256 keys x 64 dk (thread t -> row t, 128B contiguous)
    #pragma unroll
    for (int g = 0; g < 8; ++g) {
        int off = (g*16) ^ ((t & 7) << 4);
        *(short8*)&Ks[t*64 + (off >> 1)] =
            *(const short8*)&Kp[(size_t)t*DK + g*8];
    }
    __syncthreads();

    int swr = (l15 & 7) << 4;
    float* ap0 = attn + ((size_t)bh * LL + q0 + qr0 + l15) * LL + kc0;
    float* ap1 = ap0 + (size_t)16 * LL;

    #pragma unroll 4
    for (int ct = 0; ct < 16; ++ct) {
        int rb = (ct*16 + l15) * 64;
        short8 a0 = *(const short8*)&Ks[rb + (((l4*16) ^ swr) >> 1)];
        short8 a1 = *(const short8*)&Ks[rb + (((64 + l4*16) ^ swr) >> 1)];
        #pragma unroll
        for (int f = 0; f < 2; ++f) {
            f32x4 s = {0.f, 0.f, 0.f, 0.f};
            s = __builtin_amdgcn_mfma_f32_16x16x32_bf16(a0, bq0[f], s, 0, 0, 0);
            s = __builtin_amdgcn_mfma_f32_16x16x32_bf16(a1, bq1[f], s, 0, 0, 0);
            float4 o;
            o.x = exp2f(s[0]) * inv[f];
            o.y = exp2f(s[1]) * inv[f];
            o.z = exp2f(s[2]) * inv[f];
            o.w = exp2f(s[3]) * inv[f];
            *(float4*)&((f ? ap1 : ap0)[ct*16 + l4*4]) = o;
        }
    }
}

// ---------------- residual + LayerNorm ----------------
__global__ __launch_bounds__(256) void ln_kernel(
    const float* __restrict__ Y, const float* __restrict__ Res,
    const float* __restrict__ g, const float* __restrict__ bta,
    float* __restrict__ out)
{
    int row = blockIdx.x;
    int t = threadIdx.x;
    const float* yp = Y  + (size_t)row*DM;
    const float* rp = Res + (size_t)row*DM;
    float v0 = yp[t]       + rp[t];
    float v1 = yp[t + 256] + rp[t + 256];
    float s1 = v0 + v1;
    float s2 = v0*v0 + v1*v1;
    __shared__ float red1[4], red2[4];
    #pragma unroll
    for (int off = 32; off >= 1; off >>= 1) {
        s1 += __shfl_xor(s1, off);
        s2 += __shfl_xor(s2, off);
    }
    int w = t >> 6;
    if ((t & 63) == 0) { red1[w] = s1; red2[w] = s2; }
    __syncthreads();
    float mu = (red1[0]+red1[1]+red1[2]+red1[3]) * (1.0f/DM);
    float ms = (red2[0]+red2[1]+red2[2]+red2[3]) * (1.0f/DM);
    float inv = rsqrtf(ms - mu*mu + 1e-12f);
    out[(size_t)row*DM + t]       = (v0 - mu)*inv*g[t]       + bta[t];
    out[(size_t)row*DM + t + 256] = (v1 - mu)*inv*g[t + 256] + bta[t + 256];
}

extern "C" void kernel_launch(void* const* d_in, const int* in_sizes, int n_in,
                              void* d_out, int out_size, void* d_ws, size_t ws_size,
                              hipStream_t stream)
{
    const float* G[4][5];
    for (int s = 0; s < 4; ++s)
        for (int i = 0; i < 5; ++i)
            G[s][i] = (const float*)d_in[s*5 + i];
    const float* q   = (const float*)d_in[20];
    const float* k   = (const float*)d_in[21];
    const float* v   = (const float*)d_in[22];
    const float* lng = (const float*)d_in[23];
    const float* lnb = (const float*)d_in[24];

    float* out  = (float*)d_out;                         // [B,L,DM]
    float* attn = out + (size_t)BB*LL*DM;                // [B,NH,L,L]

    const size_t NTOK = (size_t)BB*LL*DM;                // 4.19M elems
    bf16* wt  = (bf16*)d_ws;                             // 4*512*512 bf16
    bf16* qbf = wt + 4*(size_t)DM*DM;                    // bf16 copies of q,k,v
    bf16* kbf = qbf + NTOK;
    bf16* vbf = kbf + NTOK;
    bf16* qh  = vbf + NTOK;                              // [bh][l][dk]
    bf16* kh  = qh + NTOK;
    bf16* vt  = kh + NTOK;                               // [bh][dk][l]
    bf16* o   = vt + NTOK;                               // [b][l][dm]
    float* y  = (float*)(o + NTOK);                      // [b][l][dm] f32
    float* invl = y + NTOK;                              // [bh][l] f32 row inv-sums

    // build all 4 W^T
    BwArgs bw;
    for (int s = 0; s < 4; ++s) {
        bw.g1[s] = G[s][0]; bw.g2[s] = G[s][1];
        bw.g3[s] = G[s][2]; bw.g4[s] = G[s][3];
        bw.wt[s] = wt + (size_t)s*DM*DM;
    }
    build_w_kernel<<<dim3(64, 4), 256, 0, stream>>>(bw);

    // q,k,v -> bf16 (16 elems/thread)
    CvtArgs cv;
    cv.src[0] = q; cv.src[1] = k; cv.src[2] = v;
    cv.dst[0] = qbf; cv.dst[1] = kbf; cv.dst[2] = vbf;
    cvt_kernel<<<dim3(NTOK/(256*16), 3), 256, 0, stream>>>(cv);

    // projections (128x64 blocks, 64x32 waves)
    QkvArgs qa;
    qa.A[0] = qbf; qa.A[1] = kbf; qa.A[2] = vbf;
    qa.W[0] = wt; qa.W[1] = wt + (size_t)DM*DM; qa.W[2] = wt + 2*(size_t)DM*DM;
    qa.bias[0] = G[0][4]; qa.bias[1] = G[1][4]; qa.bias[2] = G[2][4];
    qa.outQ = qh; qa.outK = kh; qa.outV = vt;
    gemm_qkv_kernel<<<dim3(BB*LL/128, DM/64, 3), 256, 0, stream>>>(qa);

    // attention pass A: XCD-swizzled 1D grid (512 blocks)
    attn_a_kernel<<<512, 256, 0, stream>>>(qh, kh, vt, invl, o);

    // attention pass B: XCD-swizzled 1D grid (4096 blocks)
    attn_p_kernel<<<4096, 256, 0, stream>>>(qh, kh, invl, attn);

    // fc + LN
    gemm_fc_kernel<<<dim3(BB*LL/128, DM/64), 256, 0, stream>>>(
        o, wt + 3*(size_t)DM*DM, G[3][4], y);
    ln_kernel<<<BB*LL, 256, 0, stream>>>(y, q, lng, lnb, out);
}

// Round 18
// 363.288 us; speedup vs baseline: 1.0730x; 1.0730x over previous
//
#include <hip/hip_runtime.h>
#include <hip/hip_bf16.h>
#include <math.h>

#define BB 4
#define LL 2048
#define DM 512
#define NH 8
#define DK 64
#define RANK 20

typedef __attribute__((ext_vector_type(8))) short short8;
typedef __attribute__((ext_vector_type(4))) short short4b;
typedef __attribute__((ext_vector_type(4))) float f32x4;
typedef __hip_bfloat16 bf16;

__device__ inline short to_bf(float x) {
    bf16 h = __float2bfloat16(x);
    return *reinterpret_cast<short*>(&h);
}
__device__ inline unsigned pk2(float lo, float hi) {
    return ((unsigned)(unsigned short)to_bf(hi) << 16) |
           (unsigned)(unsigned short)to_bf(lo);
}

// ---------------- build W^T (bf16) from TT cores, all 4 sets ----------------
struct BwArgs {
    const float* g1[4]; const float* g2[4]; const float* g3[4]; const float* g4[4];
    bf16* wt[4];
};
__global__ __launch_bounds__(256) void build_w_kernel(BwArgs args)
{
    int s4 = blockIdx.y;
    const float* __restrict__ g1 = args.g1[s4];
    const float* __restrict__ g2 = args.g2[s4];
    const float* __restrict__ g3 = args.g3[s4];
    const float* __restrict__ g4 = args.g4[s4];
    bf16* __restrict__ Wt = args.wt[s4];

    int idx = blockIdx.x * 256 + threadIdx.x;
    if (idx >= 4*4*8*4*4*8) return;
    int q = idx & 7; int t = idx >> 3;
    int p = t & 3;  t >>= 2;
    int o = t & 3;  t >>= 2;
    int y = t & 7;  t >>= 3;
    int x = t & 3;  t >>= 2;
    int w = t & 3;

    float c[RANK];
    for (int v = 0; v < RANK; ++v) c[v] = 0.f;
    for (int u = 0; u < RANK; ++u) {
        float a = g1[(w*4 + o)*RANK + u];
        const float* g2p = g2 + ((u*4 + x)*4 + p)*RANK;
        for (int v = 0; v < RANK; ++v) c[v] += a * g2p[v];
    }
    float d[RANK];
    for (int r = 0; r < RANK; ++r) d[r] = 0.f;
    for (int v = 0; v < RANK; ++v) {
        float cv = c[v];
        const float* g3p = g3 + ((v*8 + y)*8 + q)*RANK;
        for (int r = 0; r < RANK; ++r) d[r] += cv * g3p[r];
    }
    for (int z = 0; z < 4; ++z) {
        for (int s = 0; s < 4; ++s) {
            float acc = 0.f;
            for (int r = 0; r < RANK; ++r) acc += d[r] * g4[(r*4 + z)*4 + s];
            int i = ((w*4 + x)*8 + y)*4 + z;
            int j = ((o*4 + p)*8 + q)*4 + s;
            Wt[(size_t)j*DM + i] = __float2bfloat16(acc);
        }
    }
}

// ---------------- fp32 -> bf16 convert (q,k,v), 16 elems/thread ----------------
struct CvtArgs { const float* src[3]; bf16* dst[3]; };
__global__ __launch_bounds__(256) void cvt_kernel(CvtArgs args)
{
    int a = blockIdx.y;
    const float* __restrict__ s = args.src[a];
    bf16* __restrict__ d = args.dst[a];
    size_t i = ((size_t)blockIdx.x * 256 + threadIdx.x) * 16;
    #pragma unroll
    for (int half = 0; half < 2; ++half) {
        float4 v0 = *(const float4*)&s[i + half*8];
        float4 v1 = *(const float4*)&s[i + half*8 + 4];
        short8 h;
        h[0] = to_bf(v0.x); h[1] = to_bf(v0.y); h[2] = to_bf(v0.z); h[3] = to_bf(v0.w);
        h[4] = to_bf(v1.x); h[5] = to_bf(v1.y); h[6] = to_bf(v1.z); h[7] = to_bf(v1.w);
        *(short8*)&d[i + half*8] = h;
    }
}

// ---------------- LDS-free MFMA GEMM core: block 128x64, wave 64x32 ----------
#define GEMM_CORE128x64(Ap, Bp)                                                    \
    f32x4 acc[4][2] = {};                                                          \
    for (int k0 = 0; k0 < DM; k0 += 32) {                                          \
        short8 a[4], b[2];                                                         \
        _Pragma("unroll")                                                          \
        for (int mt = 0; mt < 4; ++mt)                                             \
            a[mt] = *(const short8*)&Ap[(size_t)(mt*16 + l15)*DM + k0 + l4*8];     \
        _Pragma("unroll")                                                          \
        for (int nt = 0; nt < 2; ++nt)                                             \
            b[nt] = *(const short8*)&Bp[(size_t)(nt*16 + l15)*DM + k0 + l4*8];     \
        _Pragma("unroll")                                                          \
        for (int mt = 0; mt < 4; ++mt)                                             \
            _Pragma("unroll")                                                      \
            for (int nt = 0; nt < 2; ++nt)                                         \
                acc[mt][nt] = __builtin_amdgcn_mfma_f32_16x16x32_bf16(             \
                    a[mt], b[nt], acc[mt][nt], 0, 0, 0);                           \
    }

// q/k/v projections fused: z=0 q (scaled by log2e/8, head layout), z=1 k,
// z=2 v (transposed [bh][d][l])
struct QkvArgs {
    const bf16* A[3]; const bf16* W[3]; const float* bias[3];
    bf16* outQ; bf16* outK; bf16* outV;
};
__global__ __launch_bounds__(256) void gemm_qkv_kernel(QkvArgs args)
{
    int z = blockIdx.z;
    const bf16* __restrict__ A  = args.A[z];
    const bf16* __restrict__ Wt = args.W[z];
    const float* __restrict__ bias = args.bias[z];

    int m0 = blockIdx.x * 128, n0 = blockIdx.y * 64;
    int t = threadIdx.x, lane = t & 63, wave = t >> 6;
    int l15 = lane & 15, l4 = lane >> 4;
    int wm = wave >> 1, wn = wave & 1;
    const bf16* Ap = A  + (size_t)(m0 + wm*64)*DM;
    const bf16* Bp = Wt + (size_t)(n0 + wn*32)*DM;

    GEMM_CORE128x64(Ap, Bp)

    if (z < 2) {
        bf16* __restrict__ out = (z == 0) ? args.outQ : args.outK;
        // 0.125 * log2(e): fold softmax scale + exp2 conversion into Q
        float oscale = (z == 0) ? 0.18033688f : 1.0f;
        #pragma unroll
        for (int mt = 0; mt < 4; ++mt) {
            #pragma unroll
            for (int r = 0; r < 4; ++r) {
                int m = m0 + wm*64 + mt*16 + l4*4 + r;
                int l = m & (LL-1), bb = m >> 11;
                #pragma unroll
                for (int nt = 0; nt < 2; ++nt) {
                    int n = n0 + wn*32 + nt*16 + l15;
                    int h = n >> 6, d = n & 63;
                    float val = (acc[mt][nt][r] + bias[n]) * oscale;
                    out[(((size_t)(bb*NH + h))*LL + l)*DK + d] = __float2bfloat16(val);
                }
            }
        }
    } else {
        // transposed store: vt[(bh*DK + d)*LL + l]
        #pragma unroll
        for (int mt = 0; mt < 4; ++mt) {
            int mbase = m0 + wm*64 + mt*16 + l4*4;
            int l = mbase & (LL-1), bb = mbase >> 11;
            #pragma unroll
            for (int nt = 0; nt < 2; ++nt) {
                int n = n0 + wn*32 + nt*16 + l15;
                int h = n >> 6, d = n & 63;
                float bv = bias[n];
                short4b h4;
                #pragma unroll
                for (int r = 0; r < 4; ++r) h4[r] = to_bf(acc[mt][nt][r] + bv);
                *(short4b*)&args.outV[((size_t)(bb*NH + h)*DK + d)*LL + l] = h4;
            }
        }
    }
}

// fc GEMM: A = o (bf16 row-major), out fp32 row-major + bias
__global__ __launch_bounds__(256) void gemm_fc_kernel(
    const bf16* __restrict__ A, const bf16* __restrict__ Wt,
    const float* __restrict__ bias, float* __restrict__ out)
{
    int m0 = blockIdx.x * 128, n0 = blockIdx.y * 64;
    int t = threadIdx.x, lane = t & 63, wave = t >> 6;
    int l15 = lane & 15, l4 = lane >> 4;
    int wm = wave >> 1, wn = wave & 1;
    const bf16* Ap = A  + (size_t)(m0 + wm*64)*DM;
    const bf16* Bp = Wt + (size_t)(n0 + wn*32)*DM;

    GEMM_CORE128x64(Ap, Bp)

    #pragma unroll
    for (int mt = 0; mt < 4; ++mt) {
        #pragma unroll
        for (int r = 0; r < 4; ++r) {
            int m = m0 + wm*64 + mt*16 + l4*4 + r;
            #pragma unroll
            for (int nt = 0; nt < 2; ++nt) {
                int n = n0 + wn*32 + nt*16 + l15;
                out[(size_t)m*DM + n] = acc[mt][nt][r] + bias[n];
            }
        }
    }
}

// ---------------- attention pass A: 32 q-rows/wave, lsum + PV + O + invl ------
// SWAPPED QK: S^T = mfma(K, Q). Each wave owns TWO Q fragments (32 q-rows) so
// every K fragment read from LDS feeds 2 MFMAs and every V fragment (register-
// prefetched once, reused for both fragments) feeds 2 PV MFMAs.
__global__ __launch_bounds__(256, 2) void attn_a_kernel(
    const bf16* __restrict__ Qh, const bf16* __restrict__ Kh,
    const bf16* __restrict__ Vt, float* __restrict__ invl_g,
    bf16* __restrict__ O)
{
    __shared__ __align__(16) bf16 Ks[128*64];       // 16 KB
    __shared__ __align__(16) bf16 Ps[4][32*128];    // 32 KB  (row q: 256B)
    __shared__ float invlS[4][32];

    int qt = blockIdx.x, bh = blockIdx.y;
    int q0 = qt * 128;
    int t = threadIdx.x, lane = t & 63, wave = t >> 6;
    int l15 = lane & 15, l4 = lane >> 4;
    int qr0 = wave * 32;

    const bf16* Qp = Qh + ((size_t)bh * LL + q0 + qr0) * DK;
    const bf16* Kp = Kh + (size_t)bh * LL * DK;
    const bf16* Vp = Vt + (size_t)bh * DK * LL;

    short8 aq0[2], aq1[2];
    #pragma unroll
    for (int f = 0; f < 2; ++f) {
        aq0[f] = *(const short8*)&Qp[(size_t)(f*16 + l15)*DK + l4*8];
        aq1[f] = *(const short8*)&Qp[(size_t)(f*16 + l15)*DK + 32 + l4*8];
    }

    int srow = t >> 3, sseg = t & 7;       // staging: 32 rows x 8 16B-segs x4
    int swr = (l15 & 7) << 4;              // swizzle key (q&7 == l15&7 for both frags)

    float lsum[2] = {0.f, 0.f};
    f32x4 o_acc[2][4] = {};

    for (int kc = 0; kc < LL; kc += 128) {
        #pragma unroll
        for (int i = 0; i < 4; ++i) {
            int row = srow + i*32;
            int off = (sseg*16) ^ ((row & 7) << 4);
            *(short8*)&Ks[row*64 + (off >> 1)] =
                *(const short8*)&Kp[(size_t)(kc + row)*DK + sseg*8];
        }
        __syncthreads();

        // prefetch V fragments for this chunk (consumed after QK -> latency hidden)
        short8 vf[16];
        #pragma unroll
        for (int kt = 0; kt < 4; ++kt)
            #pragma unroll
            for (int dt = 0; dt < 4; ++dt)
                vf[kt*4 + dt] =
                    *(const short8*)&Vp[(size_t)(dt*16 + l15)*LL + kc + kt*32 + l4*8];

        #pragma unroll
        for (int ct = 0; ct < 8; ++ct) {
            int rb = (ct*16 + l15) * 64;
            short8 k0f = *(const short8*)&Ks[rb + (((l4*16) ^ swr) >> 1)];
            short8 k1f = *(const short8*)&Ks[rb + (((64 + l4*16) ^ swr) >> 1)];
            #pragma unroll
            for (int f = 0; f < 2; ++f) {
                f32x4 s = {0.f, 0.f, 0.f, 0.f};
                s = __builtin_amdgcn_mfma_f32_16x16x32_bf16(k0f, aq0[f], s, 0, 0, 0);
                s = __builtin_amdgcn_mfma_f32_16x16x32_bf16(k1f, aq1[f], s, 0, 0, 0);
                float p0 = exp2f(s[0]), p1 = exp2f(s[1]);
                float p2 = exp2f(s[2]), p3 = exp2f(s[3]);
                lsum[f] += (p0 + p1) + (p2 + p3);
                uint2 w2;
                w2.x = pk2(p0, p1);
                w2.y = pk2(p2, p3);
                int kb = (ct*32 + l4*8) ^ swr;
                *(uint2*)((char*)&Ps[wave][(f*16 + l15)*128] + kb) = w2;
            }
        }

        #pragma unroll
        for (int f = 0; f < 2; ++f)
            #pragma unroll
            for (int kt = 0; kt < 4; ++kt) {
                short8 a = *(const short8*)
                    &Ps[wave][(f*16 + l15)*128 + (((kt*64 + l4*16) ^ swr) >> 1)];
                #pragma unroll
                for (int dt = 0; dt < 4; ++dt)
                    o_acc[f][dt] = __builtin_amdgcn_mfma_f32_16x16x32_bf16(
                        a, vf[kt*4 + dt], o_acc[f][dt], 0, 0, 0);
            }
        __syncthreads();
    }

    // reduce lsum across the 4 l4-groups (lanes sharing q = l15 within a frag)
    #pragma unroll
    for (int f = 0; f < 2; ++f) {
        float ss = lsum[f];
        ss += __shfl_xor(ss, 16);
        ss += __shfl_xor(ss, 32);
        float inv = 1.0f / ss;
        if (l4 == 0) {
            invl_g[(size_t)bh * LL + q0 + qr0 + f*16 + l15] = inv;
            invlS[wave][f*16 + l15] = inv;
        }
    }

    // write O = o_acc * invl (bf16)
    int bb = bh >> 3, h = bh & 7;
    #pragma unroll
    for (int f = 0; f < 2; ++f) {
        f32x4 iv = *(f32x4*)&invlS[wave][f*16 + l4*4];
        #pragma unroll
        for (int dt = 0; dt < 4; ++dt)
            #pragma unroll
            for (int r = 0; r < 4; ++r) {
                int row = q0 + qr0 + f*16 + l4*4 + r;
                O[((size_t)bb * LL + row) * DM + h*DK + dt*16 + l15] =
                    __float2bfloat16(o_acc[f][dt][r] * iv[r]);
            }
    }
}

// ---------------- attention pass B: normalized-P streamer, 4 Q-frags/wave ----
// Swapped operands: S^T = mfma(K, Q) -> lane holds 4 CONSECUTIVE k-columns
// for one q-row (col = l15) -> float4 stores. Each staged K-oct serves 256
// q-rows (4 fragments/wave). No barriers in the store loop.
__global__ __launch_bounds__(256, 4) void attn_p_kernel(
    const bf16* __restrict__ Qh, const bf16* __restrict__ Kh,
    const float* __restrict__ invl_g, float* __restrict__ attn)
{
    __shared__ __align__(16) bf16 Ks[256*64];       // 32 KB, swizzled rows

    int ko = blockIdx.x, qt = blockIdx.y, bh = blockIdx.z;
    int kc0 = ko * 256, q0 = qt * 256;
    int t = threadIdx.x, lane = t & 63, wave = t >> 6;
    int l15 = lane & 15, l4 = lane >> 4;
    int qr0 = wave * 64;

    const bf16* Qp = Qh + ((size_t)bh * LL + q0 + qr0) * DK;
    const bf16* Kp = Kh + ((size_t)bh * LL + kc0) * DK;

    // four Q fragments (B-operand) per wave
    short8 bq0[4], bq1[4];
    float inv[4];
    #pragma unroll
    for (int f = 0; f < 4; ++f) {
        bq0[f] = *(const short8*)&Qp[(size_t)(f*16 + l15)*DK + l4*8];
        bq1[f] = *(const short8*)&Qp[(size_t)(f*16 + l15)*DK + 32 + l4*8];
        inv[f] = invl_g[(size_t)bh * LL + q0 + qr0 + f*16 + l15];
    }

    // stage 256 keys x 64 dk (thread t -> row t, 128B contiguous)
    #pragma unroll
    for (int g = 0; g < 8; ++g) {
        int off = (g*16) ^ ((t & 7) << 4);
        *(short8*)&Ks[t*64 + (off >> 1)] =
            *(const short8*)&Kp[(size_t)t*DK + g*8];
    }
    __syncthreads();

    int swr = (l15 & 7) << 4;
    float* ap = attn + ((size_t)bh * LL + q0 + qr0 + l15) * LL + kc0;

    #pragma unroll 2
    for (int ct = 0; ct < 16; ++ct) {
        int rb = (ct*16 + l15) * 64;
        short8 a0 = *(const short8*)&Ks[rb + (((l4*16) ^ swr) >> 1)];
        short8 a1 = *(const short8*)&Ks[rb + (((64 + l4*16) ^ swr) >> 1)];
        #pragma unroll
        for (int f = 0; f < 4; ++f) {
            f32x4 s = {0.f, 0.f, 0.f, 0.f};
            s = __builtin_amdgcn_mfma_f32_16x16x32_bf16(a0, bq0[f], s, 0, 0, 0);
            s = __builtin_amdgcn_mfma_f32_16x16x32_bf16(a1, bq1[f], s, 0, 0, 0);
            float4 o;
            o.x = exp2f(s[0]) * inv[f];
            o.y = exp2f(s[1]) * inv[f];
            o.z = exp2f(s[2]) * inv[f];
            o.w = exp2f(s[3]) * inv[f];
            *(float4*)&ap[(size_t)(f*16) * LL + ct*16 + l4*4] = o;
        }
    }
}

// ---------------- residual + LayerNorm ----------------
__global__ __launch_bounds__(256) void ln_kernel(
    const float* __restrict__ Y, const float* __restrict__ Res,
    const float* __restrict__ g, const float* __restrict__ bta,
    float* __restrict__ out)
{
    int row = blockIdx.x;
    int t = threadIdx.x;
    const float* yp = Y  + (size_t)row*DM;
    const float* rp = Res + (size_t)row*DM;
    float v0 = yp[t]       + rp[t];
    float v1 = yp[t + 256] + rp[t + 256];
    float s1 = v0 + v1;
    float s2 = v0*v0 + v1*v1;
    __shared__ float red1[4], red2[4];
    #pragma unroll
    for (int off = 32; off >= 1; off >>= 1) {
        s1 += __shfl_xor(s1, off);
        s2 += __shfl_xor(s2, off);
    }
    int w = t >> 6;
    if ((t & 63) == 0) { red1[w] = s1; red2[w] = s2; }
    __syncthreads();
    float mu = (red1[0]+red1[1]+red1[2]+red1[3]) * (1.0f/DM);
    float ms = (red2[0]+red2[1]+red2[2]+red2[3]) * (1.0f/DM);
    float inv = rsqrtf(ms - mu*mu + 1e-12f);
    out[(size_t)row*DM + t]       = (v0 - mu)*inv*g[t]       + bta[t];
    out[(size_t)row*DM + t + 256] = (v1 - mu)*inv*g[t + 256] + bta[t + 256];
}

extern "C" void kernel_launch(void* const* d_in, const int* in_sizes, int n_in,
                              void* d_out, int out_size, void* d_ws, size_t ws_size,
                              hipStream_t stream)
{
    const float* G[4][5];
    for (int s = 0; s < 4; ++s)
        for (int i = 0; i < 5; ++i)
            G[s][i] = (const float*)d_in[s*5 + i];
    const float* q   = (const float*)d_in[20];
    const float* k   = (const float*)d_in[21];
    const float* v   = (const float*)d_in[22];
    const float* lng = (const float*)d_in[23];
    const float* lnb = (const float*)d_in[24];

    float* out  = (float*)d_out;                         // [B,L,DM]
    float* attn = out + (size_t)BB*LL*DM;                // [B,NH,L,L]

    const size_t NTOK = (size_t)BB*LL*DM;                // 4.19M elems
    bf16* wt  = (bf16*)d_ws;                             // 4*512*512 bf16
    bf16* qbf = wt + 4*(size_t)DM*DM;                    // bf16 copies of q,k,v
    bf16* kbf = qbf + NTOK;
    bf16* vbf = kbf + NTOK;
    bf16* qh  = vbf + NTOK;                              // [bh][l][dk]
    bf16* kh  = qh + NTOK;
    bf16* vt  = kh + NTOK;                               // [bh][dk][l]
    bf16* o   = vt + NTOK;                               // [b][l][dm]
    float* y  = (float*)(o + NTOK);                      // [b][l][dm] f32
    float* invl = y + NTOK;                              // [bh][l] f32 row inv-sums

    // build all 4 W^T
    BwArgs bw;
    for (int s = 0; s < 4; ++s) {
        bw.g1[s] = G[s][0]; bw.g2[s] = G[s][1];
        bw.g3[s] = G[s][2]; bw.g4[s] = G[s][3];
        bw.wt[s] = wt + (size_t)s*DM*DM;
    }
    build_w_kernel<<<dim3(64, 4), 256, 0, stream>>>(bw);

    // q,k,v -> bf16 (16 elems/thread)
    CvtArgs cv;
    cv.src[0] = q; cv.src[1] = k; cv.src[2] = v;
    cv.dst[0] = qbf; cv.dst[1] = kbf; cv.dst[2] = vbf;
    cvt_kernel<<<dim3(NTOK/(256*16), 3), 256, 0, stream>>>(cv);

    // projections (128x64 blocks, 64x32 waves)
    QkvArgs qa;
    qa.A[0] = qbf; qa.A[1] = kbf; qa.A[2] = vbf;
    qa.W[0] = wt; qa.W[1] = wt + (size_t)DM*DM; qa.W[2] = wt + 2*(size_t)DM*DM;
    qa.bias[0] = G[0][4]; qa.bias[1] = G[1][4]; qa.bias[2] = G[2][4];
    qa.outQ = qh; qa.outK = kh; qa.outV = vt;
    gemm_qkv_kernel<<<dim3(BB*LL/128, DM/64, 3), 256, 0, stream>>>(qa);

    // attention pass A: 128 q-rows/block, 32 q-rows/wave (round-16 grid)
    attn_a_kernel<<<dim3(LL/128, BB*NH), 256, 0, stream>>>(qh, kh, vt, invl, o);

    // attention pass B: normalized-P streamer, 256 q-rows/block
    attn_p_kernel<<<dim3(LL/256, LL/256, BB*NH), 256, 0, stream>>>(qh, kh, invl, attn);

    // fc + LN
    gemm_fc_kernel<<<dim3(BB*LL/128, DM/64), 256, 0, stream>>>(
        o, wt + 3*(size_t)DM*DM, G[3][4], y);
    ln_kernel<<<BB*LL, 256, 0, stream>>>(y, q, lng, lnb, out);
}

// Round 19
// 342.618 us; speedup vs baseline: 1.1378x; 1.0603x over previous
//
#include <hip/hip_runtime.h>
#include <hip/hip_bf16.h>
#include <math.h>

#define BB 4
#define LL 2048
#define DM 512
#define NH 8
#define DK 64
#define RANK 20

typedef __attribute__((ext_vector_type(8))) short short8;
typedef __attribute__((ext_vector_type(4))) short short4b;
typedef __attribute__((ext_vector_type(4))) float f32x4;
typedef __hip_bfloat16 bf16;

__device__ inline short to_bf(float x) {
    bf16 h = __float2bfloat16(x);
    return *reinterpret_cast<short*>(&h);
}
__device__ inline unsigned pk2(float lo, float hi) {
    return ((unsigned)(unsigned short)to_bf(hi) << 16) |
           (unsigned)(unsigned short)to_bf(lo);
}

// ---------------- build W^T (bf16) from TT cores, all 4 sets ----------------
struct BwArgs {
    const float* g1[4]; const float* g2[4]; const float* g3[4]; const float* g4[4];
    bf16* wt[4];
};
__global__ __launch_bounds__(256) void build_w_kernel(BwArgs args)
{
    int s4 = blockIdx.y;
    const float* __restrict__ g1 = args.g1[s4];
    const float* __restrict__ g2 = args.g2[s4];
    const float* __restrict__ g3 = args.g3[s4];
    const float* __restrict__ g4 = args.g4[s4];
    bf16* __restrict__ Wt = args.wt[s4];

    int idx = blockIdx.x * 256 + threadIdx.x;
    if (idx >= 4*4*8*4*4*8) return;
    int q = idx & 7; int t = idx >> 3;
    int p = t & 3;  t >>= 2;
    int o = t & 3;  t >>= 2;
    int y = t & 7;  t >>= 3;
    int x = t & 3;  t >>= 2;
    int w = t & 3;

    float c[RANK];
    for (int v = 0; v < RANK; ++v) c[v] = 0.f;
    for (int u = 0; u < RANK; ++u) {
        float a = g1[(w*4 + o)*RANK + u];
        const float* g2p = g2 + ((u*4 + x)*4 + p)*RANK;
        for (int v = 0; v < RANK; ++v) c[v] += a * g2p[v];
    }
    float d[RANK];
    for (int r = 0; r < RANK; ++r) d[r] = 0.f;
    for (int v = 0; v < RANK; ++v) {
        float cv = c[v];
        const float* g3p = g3 + ((v*8 + y)*8 + q)*RANK;
        for (int r = 0; r < RANK; ++r) d[r] += cv * g3p[r];
    }
    for (int z = 0; z < 4; ++z) {
        for (int s = 0; s < 4; ++s) {
            float acc = 0.f;
            for (int r = 0; r < RANK; ++r) acc += d[r] * g4[(r*4 + z)*4 + s];
            int i = ((w*4 + x)*8 + y)*4 + z;
            int j = ((o*4 + p)*8 + q)*4 + s;
            Wt[(size_t)j*DM + i] = __float2bfloat16(acc);
        }
    }
}

// ---------------- fp32 -> bf16 convert (q,k,v), 16 elems/thread ----------------
struct CvtArgs { const float* src[3]; bf16* dst[3]; };
__global__ __launch_bounds__(256) void cvt_kernel(CvtArgs args)
{
    int a = blockIdx.y;
    const float* __restrict__ s = args.src[a];
    bf16* __restrict__ d = args.dst[a];
    size_t i = ((size_t)blockIdx.x * 256 + threadIdx.x) * 16;
    #pragma unroll
    for (int half = 0; half < 2; ++half) {
        float4 v0 = *(const float4*)&s[i + half*8];
        float4 v1 = *(const float4*)&s[i + half*8 + 4];
        short8 h;
        h[0] = to_bf(v0.x); h[1] = to_bf(v0.y); h[2] = to_bf(v0.z); h[3] = to_bf(v0.w);
        h[4] = to_bf(v1.x); h[5] = to_bf(v1.y); h[6] = to_bf(v1.z); h[7] = to_bf(v1.w);
        *(short8*)&d[i + half*8] = h;
    }
}

// ---------------- LDS-free MFMA GEMM core: block 128x64, wave 64x32 ----------
#define GEMM_CORE128x64(Ap, Bp)                                                    \
    f32x4 acc[4][2] = {};                                                          \
    for (int k0 = 0; k0 < DM; k0 += 32) {                                          \
        short8 a[4], b[2];                                                         \
        _Pragma("unroll")                                                          \
        for (int mt = 0; mt < 4; ++mt)                                             \
            a[mt] = *(const short8*)&Ap[(size_t)(mt*16 + l15)*DM + k0 + l4*8];     \
        _Pragma("unroll")                                                          \
        for (int nt = 0; nt < 2; ++nt)                                             \
            b[nt] = *(const short8*)&Bp[(size_t)(nt*16 + l15)*DM + k0 + l4*8];     \
        _Pragma("unroll")                                                          \
        for (int mt = 0; mt < 4; ++mt)                                             \
            _Pragma("unroll")                                                      \
            for (int nt = 0; nt < 2; ++nt)                                         \
                acc[mt][nt] = __builtin_amdgcn_mfma_f32_16x16x32_bf16(             \
                    a[mt], b[nt], acc[mt][nt], 0, 0, 0);                           \
    }

// q/k/v projections fused: z=0 q (scaled by log2e/8, head layout), z=1 k,
// z=2 v (transposed [bh][d][l])
struct QkvArgs {
    const bf16* A[3]; const bf16* W[3]; const float* bias[3];
    bf16* outQ; bf16* outK; bf16* outV;
};
__global__ __launch_bounds__(256) void gemm_qkv_kernel(QkvArgs args)
{
    int z = blockIdx.z;
    const bf16* __restrict__ A  = args.A[z];
    const bf16* __restrict__ Wt = args.W[z];
    const float* __restrict__ bias = args.bias[z];

    int m0 = blockIdx.x * 128, n0 = blockIdx.y * 64;
    int t = threadIdx.x, lane = t & 63, wave = t >> 6;
    int l15 = lane & 15, l4 = lane >> 4;
    int wm = wave >> 1, wn = wave & 1;
    const bf16* Ap = A  + (size_t)(m0 + wm*64)*DM;
    const bf16* Bp = Wt + (size_t)(n0 + wn*32)*DM;

    GEMM_CORE128x64(Ap, Bp)

    if (z < 2) {
        bf16* __restrict__ out = (z == 0) ? args.outQ : args.outK;
        // 0.125 * log2(e): fold softmax scale + exp2 conversion into Q
        float oscale = (z == 0) ? 0.18033688f : 1.0f;
        #pragma unroll
        for (int mt = 0; mt < 4; ++mt) {
            #pragma unroll
            for (int r = 0; r < 4; ++r) {
                int m = m0 + wm*64 + mt*16 + l4*4 + r;
                int l = m & (LL-1), bb = m >> 11;
                #pragma unroll
                for (int nt = 0; nt < 2; ++nt) {
                    int n = n0 + wn*32 + nt*16 + l15;
                    int h = n >> 6, d = n & 63;
                    float val = (acc[mt][nt][r] + bias[n]) * oscale;
                    out[(((size_t)(bb*NH + h))*LL + l)*DK + d] = __float2bfloat16(val);
                }
            }
        }
    } else {
        // transposed store: vt[(bh*DK + d)*LL + l]
        #pragma unroll
        for (int mt = 0; mt < 4; ++mt) {
            int mbase = m0 + wm*64 + mt*16 + l4*4;
            int l = mbase & (LL-1), bb = mbase >> 11;
            #pragma unroll
            for (int nt = 0; nt < 2; ++nt) {
                int n = n0 + wn*32 + nt*16 + l15;
                int h = n >> 6, d = n & 63;
                float bv = bias[n];
                short4b h4;
                #pragma unroll
                for (int r = 0; r < 4; ++r) h4[r] = to_bf(acc[mt][nt][r] + bv);
                *(short4b*)&args.outV[((size_t)(bb*NH + h)*DK + d)*LL + l] = h4;
            }
        }
    }
}

// fc GEMM: A = o (bf16 row-major), out fp32 row-major + bias
__global__ __launch_bounds__(256) void gemm_fc_kernel(
    const bf16* __restrict__ A, const bf16* __restrict__ Wt,
    const float* __restrict__ bias, float* __restrict__ out)
{
    int m0 = blockIdx.x * 128, n0 = blockIdx.y * 64;
    int t = threadIdx.x, lane = t & 63, wave = t >> 6;
    int l15 = lane & 15, l4 = lane >> 4;
    int wm = wave >> 1, wn = wave & 1;
    const bf16* Ap = A  + (size_t)(m0 + wm*64)*DM;
    const bf16* Bp = Wt + (size_t)(n0 + wn*32)*DM;

    GEMM_CORE128x64(Ap, Bp)

    #pragma unroll
    for (int mt = 0; mt < 4; ++mt) {
        #pragma unroll
        for (int r = 0; r < 4; ++r) {
            int m = m0 + wm*64 + mt*16 + l4*4 + r;
            #pragma unroll
            for (int nt = 0; nt < 2; ++nt) {
                int n = n0 + wn*32 + nt*16 + l15;
                out[(size_t)m*DM + n] = acc[mt][nt][r] + bias[n];
            }
        }
    }
}

// ---------------- attention pass A: 32 q-rows/wave, V staged in LDS ----------
// SWAPPED QK: S^T = mfma(K, Q). K and V chunks staged cooperatively in LDS
// (XOR-swizzled), shared by all 4 waves -> V global traffic /4 and no global
// latency inside the compute loop. Each K/V fragment read feeds 2 MFMAs.
__global__ __launch_bounds__(256, 2) void attn_a_kernel(
    const bf16* __restrict__ Qh, const bf16* __restrict__ Kh,
    const bf16* __restrict__ Vt, float* __restrict__ invl_g,
    bf16* __restrict__ O)
{
    __shared__ __align__(16) bf16 Ks[128*64];       // 16 KB (128B rows)
    __shared__ __align__(16) bf16 Vs[64*128];       // 16 KB (256B rows, V^T chunk)
    __shared__ __align__(16) bf16 Ps[4][32*128];    // 32 KB (256B rows)
    __shared__ float invlS[4][32];

    int qt = blockIdx.x, bh = blockIdx.y;
    int q0 = qt * 128;
    int t = threadIdx.x, lane = t & 63, wave = t >> 6;
    int l15 = lane & 15, l4 = lane >> 4;
    int qr0 = wave * 32;

    const bf16* Qp = Qh + ((size_t)bh * LL + q0 + qr0) * DK;
    const bf16* Kp = Kh + (size_t)bh * LL * DK;
    const bf16* Vp = Vt + (size_t)bh * DK * LL;

    short8 aq0[2], aq1[2];
    #pragma unroll
    for (int f = 0; f < 2; ++f) {
        aq0[f] = *(const short8*)&Qp[(size_t)(f*16 + l15)*DK + l4*8];
        aq1[f] = *(const short8*)&Qp[(size_t)(f*16 + l15)*DK + 32 + l4*8];
    }

    int srow = t >> 3, sseg = t & 7;       // K staging: 32 rows x 8 16B-segs x4
    int swr = (l15 & 7) << 4;              // swizzle key (q&7 == l15&7 for both frags)

    float lsum[2] = {0.f, 0.f};
    f32x4 o_acc[2][4] = {};

    for (int kc = 0; kc < LL; kc += 128) {
        // stage K chunk (128 keys x 64 dk), swizzled
        #pragma unroll
        for (int i = 0; i < 4; ++i) {
            int row = srow + i*32;
            int off = (sseg*16) ^ ((row & 7) << 4);
            *(short8*)&Ks[row*64 + (off >> 1)] =
                *(const short8*)&Kp[(size_t)(kc + row)*DK + sseg*8];
        }
        // stage V^T chunk (64 d-rows x 128 keys), swizzled; coalesced 128B/8-lanes
        #pragma unroll
        for (int i = 0; i < 2; ++i) {
            int vrow = (t >> 3) + i*32;
            #pragma unroll
            for (int j = 0; j < 2; ++j) {
                int gran = (t & 7) + j*8;
                int vb = (gran*16) ^ ((vrow & 7) << 4);
                *(short8*)&Vs[vrow*128 + (vb >> 1)] =
                    *(const short8*)&Vp[(size_t)vrow*LL + kc + gran*8];
            }
        }
        __syncthreads();

        #pragma unroll
        for (int ct = 0; ct < 8; ++ct) {
            int rb = (ct*16 + l15) * 64;
            short8 k0f = *(const short8*)&Ks[rb + (((l4*16) ^ swr) >> 1)];
            short8 k1f = *(const short8*)&Ks[rb + (((64 + l4*16) ^ swr) >> 1)];
            #pragma unroll
            for (int f = 0; f < 2; ++f) {
                f32x4 s = {0.f, 0.f, 0.f, 0.f};
                s = __builtin_amdgcn_mfma_f32_16x16x32_bf16(k0f, aq0[f], s, 0, 0, 0);
                s = __builtin_amdgcn_mfma_f32_16x16x32_bf16(k1f, aq1[f], s, 0, 0, 0);
                float p0 = exp2f(s[0]), p1 = exp2f(s[1]);
                float p2 = exp2f(s[2]), p3 = exp2f(s[3]);
                lsum[f] += (p0 + p1) + (p2 + p3);
                uint2 w2;
                w2.x = pk2(p0, p1);
                w2.y = pk2(p2, p3);
                int kb = (ct*32 + l4*8) ^ swr;
                *(uint2*)((char*)&Ps[wave][(f*16 + l15)*128] + kb) = w2;
            }
        }

        #pragma unroll
        for (int f = 0; f < 2; ++f)
            #pragma unroll
            for (int kt = 0; kt < 4; ++kt) {
                short8 a = *(const short8*)
                    &Ps[wave][(f*16 + l15)*128 + (((kt*64 + l4*16) ^ swr) >> 1)];
                #pragma unroll
                for (int dt = 0; dt < 4; ++dt) {
                    short8 b = *(const short8*)
                        &Vs[(dt*16 + l15)*128 + (((kt*64 + l4*16) ^ swr) >> 1)];
                    o_acc[f][dt] = __builtin_amdgcn_mfma_f32_16x16x32_bf16(
                        a, b, o_acc[f][dt], 0, 0, 0);
                }
            }
        __syncthreads();
    }

    // reduce lsum across the 4 l4-groups (lanes sharing q = l15 within a frag)
    #pragma unroll
    for (int f = 0; f < 2; ++f) {
        float ss = lsum[f];
        ss += __shfl_xor(ss, 16);
        ss += __shfl_xor(ss, 32);
        float inv = 1.0f / ss;
        if (l4 == 0) {
            invl_g[(size_t)bh * LL + q0 + qr0 + f*16 + l15] = inv;
            invlS[wave][f*16 + l15] = inv;
        }
    }

    // write O = o_acc * invl (bf16)
    int bb = bh >> 3, h = bh & 7;
    #pragma unroll
    for (int f = 0; f < 2; ++f) {
        f32x4 iv = *(f32x4*)&invlS[wave][f*16 + l4*4];
        #pragma unroll
        for (int dt = 0; dt < 4; ++dt)
            #pragma unroll
            for (int r = 0; r < 4; ++r) {
                int row = q0 + qr0 + f*16 + l4*4 + r;
                O[((size_t)bb * LL + row) * DM + h*DK + dt*16 + l15] =
                    __float2bfloat16(o_acc[f][dt][r] * iv[r]);
            }
    }
}

// ---------------- attention pass B: normalized-P streamer, 2 Q-frags/wave ----
__global__ __launch_bounds__(256, 4) void attn_p_kernel(
    const bf16* __restrict__ Qh, const bf16* __restrict__ Kh,
    const float* __restrict__ invl_g, float* __restrict__ attn)
{
    __shared__ __align__(16) bf16 Ks[256*64];       // 32 KB, swizzled rows

    int ko = blockIdx.x, qt = blockIdx.y, bh = blockIdx.z;
    int kc0 = ko * 256, q0 = qt * 128;
    int t = threadIdx.x, lane = t & 63, wave = t >> 6;
    int l15 = lane & 15, l4 = lane >> 4;
    int qr0 = wave * 32;

    const bf16* Qp = Qh + ((size_t)bh * LL + q0 + qr0) * DK;
    const bf16* Kp = Kh + ((size_t)bh * LL + kc0) * DK;

    // two Q fragments (B-operand) per wave
    short8 bq0[2], bq1[2];
    float inv[2];
    #pragma unroll
    for (int f = 0; f < 2; ++f) {
        bq0[f] = *(const short8*)&Qp[(size_t)(f*16 + l15)*DK + l4*8];
        bq1[f] = *(const short8*)&Qp[(size_t)(f*16 + l15)*DK + 32 + l4*8];
        inv[f] = invl_g[(size_t)bh * LL + q0 + qr0 + f*16 + l15];
    }

    // stage 256 keys x 64 dk (thread t -> row t, 128B contiguous)
    #pragma unroll
    for (int g = 0; g < 8; ++g) {
        int off = (g*16) ^ ((t & 7) << 4);
        *(short8*)&Ks[t*64 + (off >> 1)] =
            *(const short8*)&Kp[(size_t)t*DK + g*8];
    }
    __syncthreads();

    int swr = (l15 & 7) << 4;
    float* ap0 = attn + ((size_t)bh * LL + q0 + qr0 + l15) * LL + kc0;
    float* ap1 = ap0 + (size_t)16 * LL;

    #pragma unroll 4
    for (int ct = 0; ct < 16; ++ct) {
        int rb = (ct*16 + l15) * 64;
        short8 a0 = *(const short8*)&Ks[rb + (((l4*16) ^ swr) >> 1)];
        short8 a1 = *(const short8*)&Ks[rb + (((64 + l4*16) ^ swr) >> 1)];
        #pragma unroll
        for (int f = 0; f < 2; ++f) {
            f32x4 s = {0.f, 0.f, 0.f, 0.f};
            s = __builtin_amdgcn_mfma_f32_16x16x32_bf16(a0, bq0[f], s, 0, 0, 0);
            s = __builtin_amdgcn_mfma_f32_16x16x32_bf16(a1, bq1[f], s, 0, 0, 0);
            float4 o;
            o.x = exp2f(s[0]) * inv[f];
            o.y = exp2f(s[1]) * inv[f];
            o.z = exp2f(s[2]) * inv[f];
            o.w = exp2f(s[3]) * inv[f];
            *(float4*)&((f ? ap1 : ap0)[ct*16 + l4*4]) = o;
        }
    }
}

// ---------------- residual + LayerNorm ----------------
__global__ __launch_bounds__(256) void ln_kernel(
    const float* __restrict__ Y, const float* __restrict__ Res,
    const float* __restrict__ g, const float* __restrict__ bta,
    float* __restrict__ out)
{
    int row = blockIdx.x;
    int t = threadIdx.x;
    const float* yp = Y  + (size_t)row*DM;
    const float* rp = Res + (size_t)row*DM;
    float v0 = yp[t]       + rp[t];
    float v1 = yp[t + 256] + rp[t + 256];
    float s1 = v0 + v1;
    float s2 = v0*v0 + v1*v1;
    __shared__ float red1[4], red2[4];
    #pragma unroll
    for (int off = 32; off >= 1; off >>= 1) {
        s1 += __shfl_xor(s1, off);
        s2 += __shfl_xor(s2, off);
    }
    int w = t >> 6;
    if ((t & 63) == 0) { red1[w] = s1; red2[w] = s2; }
    __syncthreads();
    float mu = (red1[0]+red1[1]+red1[2]+red1[3]) * (1.0f/DM);
    float ms = (red2[0]+red2[1]+red2[2]+red2[3]) * (1.0f/DM);
    float inv = rsqrtf(ms - mu*mu + 1e-12f);
    out[(size_t)row*DM + t]       = (v0 - mu)*inv*g[t]       + bta[t];
    out[(size_t)row*DM + t + 256] = (v1 - mu)*inv*g[t + 256] + bta[t + 256];
}

extern "C" void kernel_launch(void* const* d_in, const int* in_sizes, int n_in,
                              void* d_out, int out_size, void* d_ws, size_t ws_size,
                              hipStream_t stream)
{
    const float* G[4][5];
    for (int s = 0; s < 4; ++s)
        for (int i = 0; i < 5; ++i)
            G[s][i] = (const float*)d_in[s*5 + i];
    const float* q   = (const float*)d_in[20];
    const float* k   = (const float*)d_in[21];
    const float* v   = (const float*)d_in[22];
    const float* lng = (const float*)d_in[23];
    const float* lnb = (const float*)d_in[24];

    float* out  = (float*)d_out;                         // [B,L,DM]
    float* attn = out + (size_t)BB*LL*DM;                // [B,NH,L,L]

    const size_t NTOK = (size_t)BB*LL*DM;                // 4.19M elems
    bf16* wt  = (bf16*)d_ws;                             // 4*512*512 bf16
    bf16* qbf = wt + 4*(size_t)DM*DM;                    // bf16 copies of q,k,v
    bf16* kbf = qbf + NTOK;
    bf16* vbf = kbf + NTOK;
    bf16* qh  = vbf + NTOK;                              // [bh][l][dk]
    bf16* kh  = qh + NTOK;
    bf16* vt  = kh + NTOK;                               // [bh][dk][l]
    bf16* o   = vt + NTOK;                               // [b][l][dm]
    float* y  = (float*)(o + NTOK);                      // [b][l][dm] f32
    float* invl = y + NTOK;                              // [bh][l] f32 row inv-sums

    // build all 4 W^T
    BwArgs bw;
    for (int s = 0; s < 4; ++s) {
        bw.g1[s] = G[s][0]; bw.g2[s] = G[s][1];
        bw.g3[s] = G[s][2]; bw.g4[s] = G[s][3];
        bw.wt[s] = wt + (size_t)s*DM*DM;
    }
    build_w_kernel<<<dim3(64, 4), 256, 0, stream>>>(bw);

    // q,k,v -> bf16 (16 elems/thread)
    CvtArgs cv;
    cv.src[0] = q; cv.src[1] = k; cv.src[2] = v;
    cv.dst[0] = qbf; cv.dst[1] = kbf; cv.dst[2] = vbf;
    cvt_kernel<<<dim3(NTOK/(256*16), 3), 256, 0, stream>>>(cv);

    // projections (128x64 blocks, 64x32 waves)
    QkvArgs qa;
    qa.A[0] = qbf; qa.A[1] = kbf; qa.A[2] = vbf;
    qa.W[0] = wt; qa.W[1] = wt + (size_t)DM*DM; qa.W[2] = wt + 2*(size_t)DM*DM;
    qa.bias[0] = G[0][4]; qa.bias[1] = G[1][4]; qa.bias[2] = G[2][4];
    qa.outQ = qh; qa.outK = kh; qa.outV = vt;
    gemm_qkv_kernel<<<dim3(BB*LL/128, DM/64, 3), 256, 0, stream>>>(qa);

    // attention pass A: 128 q-rows/block, V staged in LDS
    attn_a_kernel<<<dim3(LL/128, BB*NH), 256, 0, stream>>>(qh, kh, vt, invl, o);

    // attention pass B: normalized-P streamer, 128 q-rows/block
    attn_p_kernel<<<dim3(LL/256, LL/128, BB*NH), 256, 0, stream>>>(qh, kh, invl, attn);

    // fc + LN
    gemm_fc_kernel<<<dim3(BB*LL/128, DM/64), 256, 0, stream>>>(
        o, wt + 3*(size_t)DM*DM, G[3][4], y);
    ln_kernel<<<BB*LL, 256, 0, stream>>>(y, q, lng, lnb, out);
}